// Round 6
// baseline (7441.261 us; speedup 1.0000x reference)
//
#include <hip/hip_runtime.h>
#include <math.h>

// Problem constants (match reference)
#define N_PTS   192000
#define NPATCH  4000      // N/48
#define PK      48        // patch size
#define NH      4         // heads
#define HD      16        // head dim

// Per-point workspace record: 320 floats (total 245.76 MB — same footprint
// as the validated R2 run, so guaranteed to fit ws_size).
//   [ 0: 64)  feat   (written k1; read k_ffn1; hid chunks 8-11 overwrite after read)
//   [64:256)  qkv    (written k1; read k_attn) -> after k_attn reused as:
//             [64:128) fmid (k_ffn1 -> k_ffn2), [128:256) hid chunks 0-7
//   [256:320) outw   (written k_attn; read k_ffn1; hid chunks 12-15 overwrite)
#define REC 320

// hid chunk ch (16 floats) lives at rec + HIDOFF(ch)
__device__ __forceinline__ int hidoff(int ch) {
    return (ch < 8) ? (128 + ch * 16) : (ch < 12 ? (ch - 8) * 16 : 256 + (ch - 12) * 16);
}

// Inline erf (Abramowitz & Stegun 7.1.26, |eps| <= 1.5e-7), no libm call.
__device__ __forceinline__ float erf_inl(float x) {
    float ax = fabsf(x);
    float t = 1.0f / fmaf(0.3275911f, ax, 1.0f);
    float poly = fmaf(1.061405429f, t, -1.453152027f);
    poly = fmaf(poly, t, 1.421413741f);
    poly = fmaf(poly, t, -0.284496736f);
    poly = fmaf(poly, t, 0.254829592f);
    poly *= t;
    float e = __expf(-ax * ax);          // native v_exp_f32
    float r = 1.0f - poly * e;
    return copysignf(r, x);
}

__device__ __forceinline__ float gelu_exact(float x) {
    return 0.5f * x * (1.0f + erf_inl(x * 0.70710678118654752f));
}

#define FMA4(acc, base, w) do { \
    (acc)[(base)+0] = fmaf(vv, (w).x, (acc)[(base)+0]); \
    (acc)[(base)+1] = fmaf(vv, (w).y, (acc)[(base)+1]); \
    (acc)[(base)+2] = fmaf(vv, (w).z, (acc)[(base)+2]); \
    (acc)[(base)+3] = fmaf(vv, (w).w, (acc)[(base)+3]); } while (0)

// ---------------------------------------------------------------------------
// K1: 1 lane = 1 point. softmax(seg)+coord -> feat -> LN1 -> qkv.
// W_in staged once in LDS; W_qkv double-buffered [64][16] chunks.
// ---------------------------------------------------------------------------
__global__ __launch_bounds__(256) void k_in_qkv(
    const float* __restrict__ seg, const float* __restrict__ coord,
    const float* __restrict__ W_in, const float* __restrict__ b_in,
    const float* __restrict__ g1, const float* __restrict__ be1,
    const float* __restrict__ W_qkv, const float* __restrict__ b_qkv,
    float* __restrict__ ws)
{
    __shared__ float sWin[23 * 64];      // 5.75 KB, staged once
    __shared__ float sWq[2][64][16];     // 8 KB, double-buffered chunks

    int tid = threadIdx.x;
    int i = blockIdx.x * 256 + tid;      // grid exact: 750*256 = N
    float* rec = ws + (size_t)i * REC;

    {
        const float4* s1 = (const float4*)W_in;
        float4* d1 = (float4*)sWin;
        for (int u = tid; u < 368; u += 256) d1[u] = s1[u];
        int c = tid >> 2, t4 = tid & 3;
        *(float4*)&sWq[0][c][t4 * 4] =
            *(const float4*)(W_qkv + (size_t)c * 192 + t4 * 4);
    }
    __syncthreads();

    // softmax(seg,20) + coord
    float iv[23];
    {
        const float* s = seg + (size_t)i * 20;
        float mx = -1e30f;
        #pragma unroll
        for (int j = 0; j < 20; ++j) { iv[j] = s[j]; mx = fmaxf(mx, iv[j]); }
        float sum = 0.f;
        #pragma unroll
        for (int j = 0; j < 20; ++j) { iv[j] = __expf(iv[j] - mx); sum += iv[j]; }
        float r = 1.f / sum;
        #pragma unroll
        for (int j = 0; j < 20; ++j) iv[j] *= r;
        iv[20] = coord[(size_t)i*3 + 0];
        iv[21] = coord[(size_t)i*3 + 1];
        iv[22] = coord[(size_t)i*3 + 2];
    }

    // feat = iv @ W_in + b_in
    float f[64];
    #pragma unroll
    for (int c = 0; c < 64; ++c) f[c] = b_in[c];
    #pragma unroll
    for (int j = 0; j < 23; ++j) {
        float vv = iv[j];
        #pragma unroll
        for (int c4 = 0; c4 < 16; ++c4) {
            float4 w = *(const float4*)&sWin[j*64 + c4*4];
            FMA4(f, c4*4, w);
        }
    }
    {   // store feat at rec+0
        float4* fd = (float4*)rec;
        #pragma unroll
        for (int c4 = 0; c4 < 16; ++c4)
            fd[c4] = make_float4(f[4*c4], f[4*c4+1], f[4*c4+2], f[4*c4+3]);
    }
    // LN1 in place
    {
        float m = 0.f;
        #pragma unroll
        for (int c = 0; c < 64; ++c) m += f[c];
        m *= (1.f/64.f);
        float v = 0.f;
        #pragma unroll
        for (int c = 0; c < 64; ++c) { float d = f[c]-m; v = fmaf(d, d, v); }
        v *= (1.f/64.f);
        float rs = 1.f / sqrtf(v + 1e-5f);
        #pragma unroll
        for (int c = 0; c < 64; ++c) f[c] = (f[c]-m)*rs*g1[c] + be1[c];
    }
    // qkv in 12 chunks of 16 outputs -> rec+64+ch*16
    int cur = 0;
    int sc = tid >> 2, st4 = tid & 3;
    for (int ch = 0; ch < 12; ++ch) {
        bool have = (ch + 1 < 12);
        float4 nw;
        if (have)
            nw = *(const float4*)(W_qkv + (size_t)sc*192 + (ch+1)*16 + st4*4);
        float a[16];
        #pragma unroll
        for (int t = 0; t < 16; ++t) a[t] = b_qkv[ch*16 + t];
        #pragma unroll
        for (int c = 0; c < 64; ++c) {
            float vv = f[c];
            #pragma unroll
            for (int q = 0; q < 4; ++q) {
                float4 w = *(const float4*)&sWq[cur][c][q*4];
                FMA4(a, q*4, w);
            }
        }
        float4* qd = (float4*)(rec + 64 + ch*16);
        #pragma unroll
        for (int q = 0; q < 4; ++q)
            qd[q] = make_float4(a[4*q], a[4*q+1], a[4*q+2], a[4*q+3]);
        __syncthreads();
        if (have) *(float4*)&sWq[cur ^ 1][sc][st4 * 4] = nw;
        __syncthreads();
        cur ^= 1;
    }
}

// ---------------------------------------------------------------------------
// K2: windowed attention — validated logic; qkv/out now at record offsets.
// ---------------------------------------------------------------------------
__global__ __launch_bounds__(256) void k_attn(
    float* __restrict__ ws, const int* __restrict__ order,
    const int* __restrict__ grid_coord, const float* __restrict__ rpe)
{
    __shared__ float q_s[NH][PK][17];
    __shared__ float k_s[NH][PK][HD];
    __shared__ float v_s[NH][PK][HD];
    __shared__ float rpe_s[276];
    __shared__ int   ord_s[PK];
    __shared__ int   gc_s[PK][3];

    int p = blockIdx.x;
    int tid = threadIdx.x;

    if (tid < PK) ord_s[tid] = order[p*PK + tid];
    for (int t = tid; t < 276; t += 256) rpe_s[t] = rpe[t];
    __syncthreads();

    if (tid < PK) {
        int row = ord_s[tid];
        gc_s[tid][0] = grid_coord[(size_t)row*3 + 0];
        gc_s[tid][1] = grid_coord[(size_t)row*3 + 1];
        gc_s[tid][2] = grid_coord[(size_t)row*3 + 2];
    }
    {
        int lane = tid & 63;
        int hh = lane >> 4, dd = lane & 15;
        for (int rr = tid >> 6; rr < PK; rr += 4) {
            const float* src = ws + (size_t)ord_s[rr] * REC + 64;   // qkv slot
            float qv = src[lane];
            float kv = src[64 + lane];
            float vv = src[128 + lane];
            q_s[hh][rr][dd] = qv;
            k_s[hh][rr][dd] = kv;
            v_s[hh][rr][dd] = vv;
        }
    }
    __syncthreads();

    int h = tid >> 6;
    int r = tid & 63;
    if (r >= PK) return;

    float qr[HD];
    #pragma unroll
    for (int d = 0; d < HD; ++d) qr[d] = q_s[h][r][d];
    int gx = gc_s[r][0], gy = gc_s[r][1], gz = gc_s[r][2];

    float s[PK];
    #pragma unroll 4
    for (int m = 0; m < PK; ++m) {
        float a = 0.f;
        #pragma unroll
        for (int d = 0; d < HD; ++d) a = fmaf(qr[d], k_s[h][m][d], a);
        a *= 0.25f;
        int i0 = min(max(gx - gc_s[m][0], -11), 11) + 11;
        int i1 = min(max(gy - gc_s[m][1], -11), 11) + 34;
        int i2 = min(max(gz - gc_s[m][2], -11), 11) + 57;
        a += rpe_s[i0*4 + h] + rpe_s[i1*4 + h] + rpe_s[i2*4 + h];
        s[m] = a;
    }

    float mx = -1e30f;
    #pragma unroll
    for (int m = 0; m < PK; ++m) mx = fmaxf(mx, s[m]);
    float sum = 0.f;
    #pragma unroll
    for (int m = 0; m < PK; ++m) { s[m] = __expf(s[m] - mx); sum += s[m]; }
    float rinv = 1.f / sum;

    float acc[HD];
    #pragma unroll
    for (int d = 0; d < HD; ++d) acc[d] = 0.f;
    #pragma unroll 4
    for (int m = 0; m < PK; ++m) {
        float pv = s[m] * rinv;
        #pragma unroll
        for (int d = 0; d < HD; ++d) acc[d] = fmaf(pv, v_s[h][m][d], acc[d]);
    }
    {
        float* dst = ws + (size_t)ord_s[r]*REC + 256 + h*HD;   // outw slot
        float4* d4 = (float4*)dst;
        #pragma unroll
        for (int d4i = 0; d4i < 4; ++d4i)
            d4[d4i] = make_float4(acc[4*d4i], acc[4*d4i+1], acc[4*d4i+2], acc[4*d4i+3]);
    }
}

// ---------------------------------------------------------------------------
// K_FFN1: attn proj + residual -> fmid; LN2 in place; FFN-up + GELU -> hid.
// Peak live ~84 floats -> real VGPRs, no AGPR shuttle, no scratch.
// All hid writes target slots this thread already finished reading.
// ---------------------------------------------------------------------------
__global__ __launch_bounds__(256) void k_ffn1(
    float* __restrict__ ws,
    const float* __restrict__ W_attn, const float* __restrict__ b_attn,
    const float* __restrict__ g2, const float* __restrict__ be2,
    const float* __restrict__ W_f1, const float* __restrict__ b_f1)
{
    __shared__ float sWa[64 * 64];       // 16 KB, W_attn staged once
    __shared__ float sW1[2][64][16];     // 8 KB,  W_f1 dbuf chunks

    int tid = threadIdx.x;
    int i = blockIdx.x * 256 + tid;
    float* rec = ws + (size_t)i * REC;
    int sc = tid >> 2, st4 = tid & 3;

    {
        const float4* s1 = (const float4*)W_attn;
        float4* d1 = (float4*)sWa;
        for (int u = tid; u < 1024; u += 256) d1[u] = s1[u];
        *(float4*)&sW1[0][sc][st4*4] =
            *(const float4*)(W_f1 + (size_t)sc*256 + st4*4);
    }
    __syncthreads();

    // attn-out projection (o = outw slot at rec+256)
    float f[64];
    #pragma unroll
    for (int c = 0; c < 64; ++c) f[c] = b_attn[c];
    for (int kc = 0; kc < 4; ++kc) {
        float o16[16];
        const float4* os = (const float4*)(rec + 256 + kc*16);
        #pragma unroll
        for (int q = 0; q < 4; ++q) {
            float4 t = os[q];
            o16[4*q]=t.x; o16[4*q+1]=t.y; o16[4*q+2]=t.z; o16[4*q+3]=t.w;
        }
        #pragma unroll
        for (int j = 0; j < 16; ++j) {
            float vv = o16[j];
            int row = kc*16 + j;
            #pragma unroll
            for (int c4 = 0; c4 < 16; ++c4) {
                float4 w = *(const float4*)&sWa[row*64 + c4*4];
                FMA4(f, c4*4, w);
            }
        }
    }
    // + residual feat (rec+0)
    {
        const float4* fs = (const float4*)rec;
        #pragma unroll
        for (int c4 = 0; c4 < 16; ++c4) {
            float4 t = fs[c4];
            f[4*c4]+=t.x; f[4*c4+1]+=t.y; f[4*c4+2]+=t.z; f[4*c4+3]+=t.w;
        }
    }
    // store fmid (post-residual, pre-LN) at rec+64
    {
        float4* fd = (float4*)(rec + 64);
        #pragma unroll
        for (int c4 = 0; c4 < 16; ++c4)
            fd[c4] = make_float4(f[4*c4], f[4*c4+1], f[4*c4+2], f[4*c4+3]);
    }
    // LN2 in place (f becomes hh)
    {
        float s0 = 0.f;
        #pragma unroll
        for (int c = 0; c < 64; ++c) s0 += f[c];
        float m = s0 * (1.f/64.f);
        float v0 = 0.f;
        #pragma unroll
        for (int c = 0; c < 64; ++c) { float d = f[c]-m; v0 = fmaf(d, d, v0); }
        float rs = 1.f / sqrtf(v0 * (1.f/64.f) + 1e-5f);
        #pragma unroll
        for (int c = 0; c < 64; ++c) f[c] = (f[c]-m)*rs*g2[c] + be2[c];
    }
    // FFN-up: hid[ch] = gelu(hh @ W_f1[:,ch] + b_f1[ch]), 16 chunks dbuf
    int cur = 0;
    for (int ch = 0; ch < 16; ++ch) {
        bool have = (ch + 1 < 16);
        float4 nw1;
        if (have)
            nw1 = *(const float4*)(W_f1 + (size_t)sc*256 + (ch+1)*16 + st4*4);
        float a[16];
        #pragma unroll
        for (int t = 0; t < 16; ++t) a[t] = b_f1[ch*16 + t];
        #pragma unroll
        for (int c = 0; c < 64; ++c) {
            float vv = f[c];
            #pragma unroll
            for (int q = 0; q < 4; ++q) {
                float4 w = *(const float4*)&sW1[cur][c][q*4];
                FMA4(a, q*4, w);
            }
        }
        float4* hd = (float4*)(rec + hidoff(ch));
        #pragma unroll
        for (int q = 0; q < 4; ++q)
            hd[q] = make_float4(gelu_exact(a[4*q]),   gelu_exact(a[4*q+1]),
                                gelu_exact(a[4*q+2]), gelu_exact(a[4*q+3]));
        __syncthreads();
        if (have) *(float4*)&sW1[cur ^ 1][sc][st4*4] = nw1;
        __syncthreads();
        cur ^= 1;
    }
}

// ---------------------------------------------------------------------------
// K_FFN2: f = fmid + b_f2 + hid @ W_f2 ; head -> out. Peak live ~96 floats.
// ---------------------------------------------------------------------------
__global__ __launch_bounds__(256) void k_ffn2(
    const float* __restrict__ ws,
    const float* __restrict__ W_f2, const float* __restrict__ b_f2,
    const float* __restrict__ W_h1, const float* __restrict__ b_h1,
    const float* __restrict__ W_h2, const float* __restrict__ b_h2,
    float* __restrict__ out)
{
    __shared__ float sH1[64 * 32];       // 8 KB, W_h1 staged once
    __shared__ float sW2[2][16][64];     // 8 KB, W_f2 dbuf chunks

    int tid = threadIdx.x;
    int i = blockIdx.x * 256 + tid;
    const float* rec = ws + (size_t)i * REC;
    int stt = tid >> 4, sc4 = tid & 15;

    {
        const float4* s2 = (const float4*)W_h1;
        float4* d2 = (float4*)sH1;
        for (int u = tid; u < 512; u += 256) d2[u] = s2[u];
        *(float4*)&sW2[0][stt][sc4*4] =
            *(const float4*)(W_f2 + (size_t)stt*64 + sc4*4);
    }
    __syncthreads();

    // f = fmid + b_f2
    float f[64];
    {
        const float4* fs = (const float4*)(rec + 64);
        #pragma unroll
        for (int c4 = 0; c4 < 16; ++c4) {
            float4 t = fs[c4];
            f[4*c4]   = t.x + b_f2[4*c4];
            f[4*c4+1] = t.y + b_f2[4*c4+1];
            f[4*c4+2] = t.z + b_f2[4*c4+2];
            f[4*c4+3] = t.w + b_f2[4*c4+3];
        }
    }
    // f += hid @ W_f2, 16 chunks dbuf
    int cur = 0;
    for (int ch = 0; ch < 16; ++ch) {
        bool have = (ch + 1 < 16);
        float4 nw2;
        if (have)
            nw2 = *(const float4*)(W_f2 + ((size_t)(ch+1)*16 + stt)*64 + sc4*4);
        float h16[16];
        {
            const float4* hs = (const float4*)(rec + hidoff(ch));
            #pragma unroll
            for (int q = 0; q < 4; ++q) {
                float4 t = hs[q];
                h16[4*q]=t.x; h16[4*q+1]=t.y; h16[4*q+2]=t.z; h16[4*q+3]=t.w;
            }
        }
        #pragma unroll
        for (int t = 0; t < 16; ++t) {
            float vv = h16[t];
            #pragma unroll
            for (int c4 = 0; c4 < 16; ++c4) {
                float4 w = *(const float4*)&sW2[cur][t][c4*4];
                FMA4(f, c4*4, w);
            }
        }
        __syncthreads();
        if (have) *(float4*)&sW2[cur ^ 1][stt][sc4*4] = nw2;
        __syncthreads();
        cur ^= 1;
    }
    // head: gelu(f @ W_h1 + b_h1) @ W_h2 + b_h2
    float g[32];
    #pragma unroll
    for (int t = 0; t < 32; ++t) g[t] = 0.f;
    #pragma unroll
    for (int c = 0; c < 64; ++c) {
        float vv = f[c];
        #pragma unroll
        for (int q = 0; q < 8; ++q) {
            float4 w = *(const float4*)&sH1[c*32 + q*4];
            FMA4(g, q*4, w);
        }
    }
    #pragma unroll
    for (int t = 0; t < 32; ++t) g[t] = gelu_exact(g[t] + b_h1[t]);
    float r0 = b_h2[0], r1 = b_h2[1], r2 = b_h2[2];
    #pragma unroll
    for (int t = 0; t < 32; ++t) {
        float gv = g[t];
        r0 = fmaf(gv, W_h2[t*3 + 0], r0);
        r1 = fmaf(gv, W_h2[t*3 + 1], r1);
        r2 = fmaf(gv, W_h2[t*3 + 2], r2);
    }
    out[(size_t)i*3 + 0] = r0;
    out[(size_t)i*3 + 1] = r1;
    out[(size_t)i*3 + 2] = r2;
}

// ---------------------------------------------------------------------------
extern "C" void kernel_launch(void* const* d_in, const int* in_sizes, int n_in,
                              void* d_out, int out_size, void* d_ws, size_t ws_size,
                              hipStream_t stream)
{
    const float* seg    = (const float*)d_in[0];
    const float* coord  = (const float*)d_in[1];
    const int*   order  = (const int*)d_in[2];
    const int*   gc     = (const int*)d_in[4];
    const float* W_in   = (const float*)d_in[5];
    const float* b_in   = (const float*)d_in[6];
    const float* g1     = (const float*)d_in[7];
    const float* be1    = (const float*)d_in[8];
    const float* W_qkv  = (const float*)d_in[9];
    const float* b_qkv  = (const float*)d_in[10];
    const float* rpe    = (const float*)d_in[11];
    const float* W_attn = (const float*)d_in[12];
    const float* b_attn = (const float*)d_in[13];
    const float* g2     = (const float*)d_in[14];
    const float* be2    = (const float*)d_in[15];
    const float* W_f1   = (const float*)d_in[16];
    const float* b_f1   = (const float*)d_in[17];
    const float* W_f2   = (const float*)d_in[18];
    const float* b_f2   = (const float*)d_in[19];
    const float* W_h1   = (const float*)d_in[20];
    const float* b_h1   = (const float*)d_in[21];
    const float* W_h2   = (const float*)d_in[22];
    const float* b_h2   = (const float*)d_in[23];

    float* ws = (float*)d_ws;   // N * 320 floats = 245.76 MB

    k_in_qkv<<<N_PTS/256, 256, 0, stream>>>(seg, coord, W_in, b_in, g1, be1,
                                            W_qkv, b_qkv, ws);
    k_attn<<<NPATCH, 256, 0, stream>>>(ws, order, gc, rpe);
    k_ffn1<<<N_PTS/256, 256, 0, stream>>>(ws, W_attn, b_attn, g2, be2,
                                          W_f1, b_f1);
    k_ffn2<<<N_PTS/256, 256, 0, stream>>>(ws, W_f2, b_f2,
                                          W_h1, b_h1, W_h2, b_h2, (float*)d_out);
}

// Round 8
// 749.704 us; speedup vs baseline: 9.9256x; 9.9256x over previous
//
#include <hip/hip_runtime.h>
#include <hip/hip_fp16.h>
#include <math.h>

// Problem constants (match reference)
#define N_PTS   192000
#define NPATCH  4000      // N/48
#define PK      48        // patch size
#define NH      4         // heads
#define HD      16        // head dim

// Inline erf (Abramowitz & Stegun 7.1.26, |eps| <= 1.5e-7), no libm call.
__device__ __forceinline__ float erf_inl(float x) {
    float ax = fabsf(x);
    float t = 1.0f / fmaf(0.3275911f, ax, 1.0f);
    float poly = fmaf(1.061405429f, t, -1.453152027f);
    poly = fmaf(poly, t, 1.421413741f);
    poly = fmaf(poly, t, -0.284496736f);
    poly = fmaf(poly, t, 0.254829592f);
    poly *= t;
    float e = __expf(-ax * ax);          // native v_exp_f32
    float r = 1.0f - poly * e;
    return copysignf(r, x);
}

__device__ __forceinline__ float gelu_exact(float x) {
    return 0.5f * x * (1.0f + erf_inl(x * 0.70710678118654752f));
}

// ---------------------------------------------------------------------------
// K1: per-point (lane=point): softmax(seg,20)+coord -> feat -> LN1 -> qkv
// EXACT R2-validated version (weights via wave-uniform scalar loads).
// ---------------------------------------------------------------------------
__global__ __launch_bounds__(256) void k_in_qkv(
    const float* __restrict__ seg, const float* __restrict__ coord,
    const float* __restrict__ W_in, const float* __restrict__ b_in,
    const float* __restrict__ g1, const float* __restrict__ be1,
    const float* __restrict__ W_qkv, const float* __restrict__ b_qkv,
    float* __restrict__ feat_out, float* __restrict__ qkv_out)
{
    int i = blockIdx.x * 256 + threadIdx.x;
    if (i >= N_PTS) return;

    float iv[23];
    {
        const float* s = seg + (size_t)i * 20;
        float mx = -1e30f;
        #pragma unroll
        for (int j = 0; j < 20; ++j) { iv[j] = s[j]; mx = fmaxf(mx, iv[j]); }
        float sum = 0.f;
        #pragma unroll
        for (int j = 0; j < 20; ++j) { iv[j] = __expf(iv[j] - mx); sum += iv[j]; }
        float r = 1.f / sum;
        #pragma unroll
        for (int j = 0; j < 20; ++j) iv[j] *= r;
        iv[20] = coord[(size_t)i*3 + 0];
        iv[21] = coord[(size_t)i*3 + 1];
        iv[22] = coord[(size_t)i*3 + 2];
    }

    // feat = iv @ W_in + b_in   (23x64), W_in row-major [23][64]
    float f[64];
    #pragma unroll
    for (int c = 0; c < 64; ++c) {
        float a = b_in[c];
        #pragma unroll
        for (int j = 0; j < 23; ++j) a = fmaf(iv[j], W_in[j*64 + c], a);
        f[c] = a;
    }
    // store feat (residual use in K3)
    {
        float4* fd = (float4*)(feat_out + (size_t)i * 64);
        #pragma unroll
        for (int c4 = 0; c4 < 16; ++c4)
            fd[c4] = make_float4(f[4*c4], f[4*c4+1], f[4*c4+2], f[4*c4+3]);
    }
    // LN1
    {
        float m = 0.f;
        #pragma unroll
        for (int c = 0; c < 64; ++c) m += f[c];
        m *= (1.f/64.f);
        float v = 0.f;
        #pragma unroll
        for (int c = 0; c < 64; ++c) { float d = f[c]-m; v = fmaf(d, d, v); }
        v *= (1.f/64.f);
        float rs = 1.f / sqrtf(v + 1e-5f);
        #pragma unroll
        for (int c = 0; c < 64; ++c) f[c] = (f[c]-m)*rs*g1[c] + be1[c];
    }
    // qkv = h @ W_qkv + b_qkv   (64x192), W_qkv row-major [64][192]
    {
        float* qd = qkv_out + (size_t)i * 192;
        for (int t4 = 0; t4 < 48; ++t4) {
            const float* bq = b_qkv + t4*4;
            float ax = bq[0], ay = bq[1], az = bq[2], aw = bq[3];
            const float* w = W_qkv + t4*4;
            #pragma unroll
            for (int c = 0; c < 64; ++c) {
                float h = f[c];
                const float* wr = w + c*192;
                ax = fmaf(h, wr[0], ax); ay = fmaf(h, wr[1], ay);
                az = fmaf(h, wr[2], az); aw = fmaf(h, wr[3], aw);
            }
            ((float4*)qd)[t4] = make_float4(ax, ay, az, aw);
        }
    }
}

// ---------------------------------------------------------------------------
// K2: windowed attention — EXACT R2-validated version.
// ---------------------------------------------------------------------------
__global__ __launch_bounds__(256) void k_attn(
    const float* __restrict__ qkv, const int* __restrict__ order,
    const int* __restrict__ grid_coord, const float* __restrict__ rpe,
    float* __restrict__ outb)
{
    __shared__ float q_s[NH][PK][17];
    __shared__ float k_s[NH][PK][HD];
    __shared__ float v_s[NH][PK][HD];
    __shared__ float rpe_s[276];
    __shared__ int   ord_s[PK];
    __shared__ int   gc_s[PK][3];

    int p = blockIdx.x;
    int tid = threadIdx.x;

    if (tid < PK) ord_s[tid] = order[p*PK + tid];
    for (int t = tid; t < 276; t += 256) rpe_s[t] = rpe[t];
    __syncthreads();

    if (tid < PK) {
        int row = ord_s[tid];
        gc_s[tid][0] = grid_coord[(size_t)row*3 + 0];
        gc_s[tid][1] = grid_coord[(size_t)row*3 + 1];
        gc_s[tid][2] = grid_coord[(size_t)row*3 + 2];
    }
    {
        int lane = tid & 63;
        int hh = lane >> 4, dd = lane & 15;
        for (int rr = tid >> 6; rr < PK; rr += 4) {
            const float* src = qkv + (size_t)ord_s[rr] * 192;
            float qv = src[lane];
            float kv = src[64 + lane];
            float vv = src[128 + lane];
            q_s[hh][rr][dd] = qv;
            k_s[hh][rr][dd] = kv;
            v_s[hh][rr][dd] = vv;
        }
    }
    __syncthreads();

    int h = tid >> 6;
    int r = tid & 63;
    if (r >= PK) return;

    float qr[HD];
    #pragma unroll
    for (int d = 0; d < HD; ++d) qr[d] = q_s[h][r][d];
    int gx = gc_s[r][0], gy = gc_s[r][1], gz = gc_s[r][2];

    float s[PK];
    #pragma unroll 4
    for (int m = 0; m < PK; ++m) {
        float a = 0.f;
        #pragma unroll
        for (int d = 0; d < HD; ++d) a = fmaf(qr[d], k_s[h][m][d], a);
        a *= 0.25f;
        int i0 = min(max(gx - gc_s[m][0], -11), 11) + 11;
        int i1 = min(max(gy - gc_s[m][1], -11), 11) + 34;
        int i2 = min(max(gz - gc_s[m][2], -11), 11) + 57;
        a += rpe_s[i0*4 + h] + rpe_s[i1*4 + h] + rpe_s[i2*4 + h];
        s[m] = a;
    }

    float mx = -1e30f;
    #pragma unroll
    for (int m = 0; m < PK; ++m) mx = fmaxf(mx, s[m]);
    float sum = 0.f;
    #pragma unroll
    for (int m = 0; m < PK; ++m) { s[m] = __expf(s[m] - mx); sum += s[m]; }
    float rinv = 1.f / sum;

    float acc[HD];
    #pragma unroll
    for (int d = 0; d < HD; ++d) acc[d] = 0.f;
    #pragma unroll 4
    for (int m = 0; m < PK; ++m) {
        float pv = s[m] * rinv;
        #pragma unroll
        for (int d = 0; d < HD; ++d) acc[d] = fmaf(pv, v_s[h][m][d], acc[d]);
    }
    {
        float* dst = outb + (size_t)ord_s[r]*64 + h*HD;
        float4* d4 = (float4*)dst;
        #pragma unroll
        for (int d4i = 0; d4i < 4; ++d4i)
            d4[d4i] = make_float4(acc[4*d4i], acc[4*d4i+1], acc[4*d4i+2], acc[4*d4i+3]);
    }
}

// ---------------------------------------------------------------------------
// K3: R2-validated kernel with ONE change: hh[64] lives in fp16 LDS
// (own column per thread, no barriers, conflict-free) instead of registers.
// Live set drops ~144 -> ~90 floats => no AGPR shuttle, no scratch.
// Weights stay on the validated wave-uniform scalar-load path.
// ---------------------------------------------------------------------------
__global__ __launch_bounds__(256) void k_ffn(
    const float* __restrict__ outb, const float* __restrict__ featb,
    const float* __restrict__ W_attn, const float* __restrict__ b_attn,
    const float* __restrict__ g2, const float* __restrict__ be2,
    const float* __restrict__ W_f1, const float* __restrict__ b_f1,
    const float* __restrict__ W_f2, const float* __restrict__ b_f2,
    const float* __restrict__ W_h1, const float* __restrict__ b_h1,
    const float* __restrict__ W_h2, const float* __restrict__ b_h2,
    float* __restrict__ out)
{
    __shared__ __half shh[64][256];   // 32 KB; hh[c] of thread t at [c][t]

    int tid = threadIdx.x;
    int i = blockIdx.x * 256 + tid;
    if (i >= N_PTS) return;

    float o[64];
    {
        const float4* os = (const float4*)(outb + (size_t)i * 64);
        #pragma unroll
        for (int c4 = 0; c4 < 16; ++c4) {
            float4 t = os[c4];
            o[4*c4]=t.x; o[4*c4+1]=t.y; o[4*c4+2]=t.z; o[4*c4+3]=t.w;
        }
    }
    // attn_out = o @ W_attn + b_attn  (64x64)
    float f[64];
    #pragma unroll
    for (int c = 0; c < 64; ++c) {
        float a = b_attn[c];
        #pragma unroll
        for (int k = 0; k < 64; ++k) a = fmaf(o[k], W_attn[k*64 + c], a);
        f[c] = a;
    }
    // + residual feat
    {
        const float4* fs = (const float4*)(featb + (size_t)i * 64);
        #pragma unroll
        for (int c4 = 0; c4 < 16; ++c4) {
            float4 t = fs[c4];
            f[4*c4]+=t.x; f[4*c4+1]+=t.y; f[4*c4+2]+=t.z; f[4*c4+3]+=t.w;
        }
    }
    // LN2 -> hh stored to own LDS column (same-thread RAW only, no barrier)
    {
        float m = 0.f;
        #pragma unroll
        for (int c = 0; c < 64; ++c) m += f[c];
        m *= (1.f/64.f);
        float v = 0.f;
        #pragma unroll
        for (int c = 0; c < 64; ++c) { float d = f[c]-m; v = fmaf(d, d, v); }
        v *= (1.f/64.f);
        float rs = 1.f / sqrtf(v + 1e-5f);
        #pragma unroll
        for (int c = 0; c < 64; ++c)
            shh[c][tid] = __float2half((f[c]-m)*rs*g2[c] + be2[c]);
    }
    // FFN residual: f += gelu(hh@W_f1+b_f1)@W_f2 + b_f2 ; chunked 16 cols
    #pragma unroll
    for (int c = 0; c < 64; ++c) f[c] += b_f2[c];
    for (int t0 = 0; t0 < 16; ++t0) {
        float a[16];
        #pragma unroll
        for (int tt = 0; tt < 16; ++tt) a[tt] = b_f1[t0*16 + tt];
        #pragma unroll
        for (int c = 0; c < 64; ++c) {
            float hv = __half2float(shh[c][tid]);
            const float* w = W_f1 + c*256 + t0*16;
            #pragma unroll
            for (int tt = 0; tt < 16; ++tt) a[tt] = fmaf(hv, w[tt], a[tt]);
        }
        #pragma unroll
        for (int tt = 0; tt < 16; ++tt) a[tt] = gelu_exact(a[tt]);
        #pragma unroll
        for (int tt = 0; tt < 16; ++tt) {
            float av = a[tt];
            const float* w2 = W_f2 + (t0*16 + tt)*64;
            #pragma unroll
            for (int c = 0; c < 64; ++c) f[c] = fmaf(av, w2[c], f[c]);
        }
    }
    // head: gelu(f@W_h1+b_h1) @ W_h2 + b_h2
    float g[32];
    #pragma unroll
    for (int t = 0; t < 32; ++t) {
        float a = b_h1[t];
        #pragma unroll
        for (int c = 0; c < 64; ++c) a = fmaf(f[c], W_h1[c*32 + t], a);
        g[t] = gelu_exact(a);
    }
    #pragma unroll
    for (int r = 0; r < 3; ++r) {
        float a = b_h2[r];
        #pragma unroll
        for (int t = 0; t < 32; ++t) a = fmaf(g[t], W_h2[t*3 + r], a);
        out[(size_t)i*3 + r] = a;
    }
}

// ---------------------------------------------------------------------------
extern "C" void kernel_launch(void* const* d_in, const int* in_sizes, int n_in,
                              void* d_out, int out_size, void* d_ws, size_t ws_size,
                              hipStream_t stream)
{
    const float* seg    = (const float*)d_in[0];
    const float* coord  = (const float*)d_in[1];
    const int*   order  = (const int*)d_in[2];
    const int*   gc     = (const int*)d_in[4];
    const float* W_in   = (const float*)d_in[5];
    const float* b_in   = (const float*)d_in[6];
    const float* g1     = (const float*)d_in[7];
    const float* be1    = (const float*)d_in[8];
    const float* W_qkv  = (const float*)d_in[9];
    const float* b_qkv  = (const float*)d_in[10];
    const float* rpe    = (const float*)d_in[11];
    const float* W_attn = (const float*)d_in[12];
    const float* b_attn = (const float*)d_in[13];
    const float* g2     = (const float*)d_in[14];
    const float* be2    = (const float*)d_in[15];
    const float* W_f1   = (const float*)d_in[16];
    const float* b_f1   = (const float*)d_in[17];
    const float* W_f2   = (const float*)d_in[18];
    const float* b_f2   = (const float*)d_in[19];
    const float* W_h1   = (const float*)d_in[20];
    const float* b_h1   = (const float*)d_in[21];
    const float* W_h2   = (const float*)d_in[22];
    const float* b_h2   = (const float*)d_in[23];

    // workspace layout (fp32): feat[N*64] | qkv[N*192] | attn_out[N*64]
    float* feat = (float*)d_ws;
    float* qkvb = feat + (size_t)N_PTS * 64;
    float* outw = qkvb + (size_t)N_PTS * 192;

    k_in_qkv<<<N_PTS/256, 256, 0, stream>>>(seg, coord, W_in, b_in, g1, be1,
                                            W_qkv, b_qkv, feat, qkvb);
    k_attn<<<NPATCH, 256, 0, stream>>>(qkvb, order, gc, rpe, outw);
    k_ffn<<<N_PTS/256, 256, 0, stream>>>(outw, feat, W_attn, b_attn, g2, be2,
                                         W_f1, b_f1, W_f2, b_f2,
                                         W_h1, b_h1, W_h2, b_h2, (float*)d_out);
}